// Round 22
// baseline (202.590 us; speedup 1.0000x reference)
//
#include <hip/hip_runtime.h>

typedef unsigned short u16;
typedef __attribute__((ext_vector_type(8))) __bf16 bf16x8;
typedef __attribute__((ext_vector_type(2))) __bf16 bf16x2;
typedef __attribute__((ext_vector_type(4))) float f32x4;
typedef __attribute__((ext_vector_type(16))) float f32x16;
typedef __attribute__((ext_vector_type(2))) unsigned u32x2;

#define NB 2
#define NS 2048
#define ND 2048
#define NH 16
#define NKH 2
#define NHD 128
#define NQKV 2560
// 1/sqrt(128) * log2(e): scores in log2 domain -> exp2f = raw v_exp_f32
#define QSCALE (0.08838834764831845f * 1.4426950408889634f)

#define AS1 __attribute__((address_space(1)))
#define AS3 __attribute__((address_space(3)))

__device__ __forceinline__ u16 f2bf(float x) {
    union { float f; unsigned u; } v; v.f = x;
    unsigned r = v.u + 0x7fffu + ((v.u >> 16) & 1u);
    return (u16)(r >> 16);
}
__device__ __forceinline__ float bf2f(u16 x) {
    union { unsigned u; float f; } v; v.u = ((unsigned)x) << 16;
    return v.f;
}
__device__ __forceinline__ unsigned pk2(float lo, float hi_) {
    union { bf16x2 v; unsigned u; } t;
    t.v.x = (__bf16)lo; t.v.y = (__bf16)hi_;
    return t.u;
}
__device__ __forceinline__ void pl32swap(unsigned &a, unsigned &b) {
#if __has_builtin(__builtin_amdgcn_permlane32_swap)
    u32x2 r = __builtin_amdgcn_permlane32_swap(a, b, false, false);
    a = r.x; b = r.y;
#else
    asm volatile("v_permlane32_swap_b32 %0, %1" : "+v"(a), "+v"(b));
#endif
}
__device__ __forceinline__ float fbits(unsigned u) {
    union { unsigned u; float f; } v; v.u = u; return v.f;
}
__device__ __forceinline__ unsigned ubits(float f) {
    union { float f; unsigned u; } v; v.f = f; return v.u;
}
__device__ __forceinline__ float redmax32(float x) {
    unsigned a = ubits(x), b = a;
    pl32swap(a, b);
    return fmaxf(fbits(a), fbits(b));
}
__device__ __forceinline__ float redsum32(float x) {
    unsigned a = ubits(x), b = a;
    pl32swap(a, b);
    return fbits(a) + fbits(b);
}

// ---------------- fp32 -> bf16 conversion: all three inputs, one launch ----------------
__global__ void cvt_all(const float* __restrict__ a, u16* __restrict__ oa, int na,
                        const float* __restrict__ b, u16* __restrict__ ob, int nb,
                        const float* __restrict__ c, u16* __restrict__ oc, int nc)
{
    int i = blockIdx.x * 256 + threadIdx.x;
    const float* src; u16* dst;
    if (i < na)            { src = a; dst = oa; }
    else if (i < na + nb)  { src = b; dst = ob; i -= na; }
    else if (i < na + nb + nc) { src = c; dst = oc; i -= na + nb; }
    else return;
    float4 v = ((const float4*)src)[i];
    ushort4 o;
    o.x = f2bf(v.x); o.y = f2bf(v.y); o.z = f2bf(v.z); o.w = f2bf(v.w);
    ((ushort4*)dst)[i] = o;
}

// ---------------- GEMM: C[M,N] = A[M,K] * B[N,K]^T (+bias), XCD-swizzled 1D grid ----------------
// Tile = 128 x (NJ*32). NJ=4: 128x128 (gemm2). NJ=5: 128x160 (gemm1, 512 blocks = 2/CU).
template<int BIAS, int OUTBF16, int NJ>
__global__ __launch_bounds__(256, 2)
void gemm_bt(const u16* __restrict__ A, const u16* __restrict__ B,
             const float* __restrict__ bias, void* __restrict__ Cout,
             int M, int N, int K, int mt, int nwg)
{
    __shared__ u16 ldsA[2][8192];            // A tile: [128 rows][64 k]
    __shared__ u16 ldsB[2][NJ * 2048];       // B tile: [NJ*32 rows][64 k]
    const int l = threadIdx.x & 63;
    const int w = threadIdx.x >> 6;
    const int bid = blockIdx.x;
    const int wg = (bid & 7) * (nwg >> 3) + (bid >> 3);
    const int m0 = (wg % mt) * 128, n0 = (wg / mt) * (NJ * 32);
    const int wm = (w >> 1) * 64, wn = (w & 1) * (NJ * 16);
    f32x4 acc[4][NJ] = {};

    const int lbyte = ((l & 7) * 16) ^ ((l >> 3) << 4);

    auto stage = [&](int buf, int k0) {
        #pragma unroll
        for (int inst = 0; inst < 4; ++inst) {
            int row = inst * 32 + w * 8 + (l >> 3);
            const u16* sa = A + (size_t)(m0 + row) * K + k0 + (lbyte >> 1);
            __builtin_amdgcn_global_load_lds(
                (const AS1 void*)sa,
                (AS3 void*)&ldsA[buf][inst * 2048 + w * 512], 16, 0, 0);
        }
        #pragma unroll
        for (int inst = 0; inst < NJ; ++inst) {
            int row = inst * 32 + w * 8 + (l >> 3);
            const u16* sb = B + (size_t)(n0 + row) * K + k0 + (lbyte >> 1);
            __builtin_amdgcn_global_load_lds(
                (const AS1 void*)sb,
                (AS3 void*)&ldsB[buf][inst * 2048 + w * 512], 16, 0, 0);
        }
    };

    auto compute = [&](int buf) {
        const char* Ab = (const char*)&ldsA[buf][0];
        const char* Bb = (const char*)&ldsB[buf][0];
        #pragma unroll
        for (int kk = 0; kk < 2; ++kk) {
            int ac2 = kk * 64 + (l >> 4) * 16;
            bf16x8 af[4], bfr[NJ];
            #pragma unroll
            for (int i = 0; i < 4; ++i) {
                int ar = wm + i * 16 + (l & 15);
                af[i] = *(const bf16x8*)(Ab + ar * 128 + (ac2 ^ ((ar & 7) << 4)));
            }
            #pragma unroll
            for (int j = 0; j < NJ; ++j) {
                int br = wn + j * 16 + (l & 15);
                bfr[j] = *(const bf16x8*)(Bb + br * 128 + (ac2 ^ ((br & 7) << 4)));
            }
            #pragma unroll
            for (int i = 0; i < 4; ++i)
                #pragma unroll
                for (int j = 0; j < NJ; ++j)
                    acc[i][j] = __builtin_amdgcn_mfma_f32_16x16x32_bf16(af[i], bfr[j], acc[i][j], 0, 0, 0);
        }
    };

    stage(0, 0);
    const int NT = K >> 6;
    for (int kt = 0; kt < NT; ++kt) {
        __syncthreads();
        if (kt + 1 < NT) stage((kt + 1) & 1, (kt + 1) << 6);
        compute(kt & 1);
    }

    #pragma unroll
    for (int j = 0; j < NJ; ++j) {
        int col = n0 + wn + j * 16 + (l & 15);
        float bv = BIAS ? bias[col] : 0.0f;
        #pragma unroll
        for (int i = 0; i < 4; ++i) {
            int row = m0 + wm + i * 16 + (l >> 4) * 4;
            #pragma unroll
            for (int r = 0; r < 4; ++r) {
                float v = acc[i][j][r] + bv;
                if (OUTBF16)
                    ((u16*)Cout)[(size_t)(row + r) * N + col] = f2bf(v);
                else
                    ((float*)Cout)[(size_t)(row + r) * N + col] = v;
            }
        }
    }
}

// ---------------- RoPE + scatter, cos/sin-deduplicated ----------------
__global__ __launch_bounds__(256)
void rope_scatter2(const u16* __restrict__ qkv,
                   const float* __restrict__ cosb,
                   const float* __restrict__ sinb,
                   u16* __restrict__ Q, u16* __restrict__ Kb, u16* __restrict__ Vt)
{
    int n = blockIdx.x * 256 + threadIdx.x;       // [0, NB*NS*128)
    const int d = n & 127;
    const int bs = n >> 7;                        // b*NS + s
    const int b = bs >> 11, s = bs & 2047;

    const float cs = cosb[(size_t)bs * NHD + d];
    const float sn = sinb[(size_t)bs * NHD + d];
    const int pd = (d < 64) ? d + 64 : d - 64;
    const float psign = (d < 64) ? -1.0f : 1.0f;

    const u16* row = qkv + (size_t)bs * NQKV;

    #pragma unroll
    for (int h = 0; h < NH; ++h) {
        float x = bf2f(row[h * NHD + d]);
        float p = bf2f(row[h * NHD + pd]);
        float v = (x * cs + psign * p * sn) * QSCALE;
        Q[(((size_t)b * NH + h) * NS + s) * NHD + d] = f2bf(v);
    }
    #pragma unroll
    for (int kh = 0; kh < NKH; ++kh) {
        float x = bf2f(row[NH * NHD + kh * NHD + d]);
        float p = bf2f(row[NH * NHD + kh * NHD + pd]);
        float v = x * cs + psign * p * sn;
        Kb[(((size_t)b * NKH + kh) * NS + s) * NHD + d] = f2bf(v);
    }
    #pragma unroll
    for (int vh = 0; vh < NKH; ++vh) {
        Vt[(((size_t)b * NKH + vh) * NHD + d) * NS + s] = row[(NH + NKH) * NHD + vh * NHD + d];
    }
}

// ---------------- causal GQA flash attention v14: counted-vmcnt pipeline (T4) ----------------
// v13 mapping/math byte-identical; sync restructured: raw s_barrier + counted
// s_waitcnt vmcnt(N). K(t+1) staged one iteration early (stays in flight a full
// iteration); V(t+1) staged post-PV (in flight across QK+softmax). Barriers
// never drain the young prefetch (old __syncthreads = vmcnt(0) drain).
// Ledger per wave (stage = 4 loads): pre-PV needs V(t) -> vmcnt(4) [K(t+1)
// still flying]; end-of-iter needs K(t+1) -> vmcnt(8) [V(t+1)+K(t+2) flying].
__global__ __launch_bounds__(256, 2)
void attn_fwd14(const u16* __restrict__ Q, const u16* __restrict__ Kb,
                const u16* __restrict__ Vt, u16* __restrict__ Out)
{
    __shared__ u16 kl[2][8192];   // K tile: [64 rows][128 d] bf16, double-buffered
    __shared__ u16 vl[8192];      // V tile: [128 d][64 kv] bf16, single-buffered

    const int l = threadIdx.x & 63;
    const int w = threadIdx.x >> 6;
    const int bid = blockIdx.x;
    const int gi = bid >> 3;
    const int g = (gi < 32) ? (63 - gi) : (gi - 32);   // sweep1: 63..32, sweep2: 0..31
    const int rem = bid & 7;                  // (b, kh, pair)
    const int b = rem & 1;
    const int kh = (rem >> 1) & 1;
    const int h = kh * 8 + ((rem >> 2) & 1) * 4 + w;   // this wave's q-head
    const int c = l & 31, hi = l >> 5;
    const int q0 = g * 32;                    // all 4 waves: same 32 q-rows
    const int qend = q0 + 31;

    const u16* Qp = Q + (((size_t)b * NH + h) * NS + q0) * NHD;
    const u16* Kp = Kb + ((size_t)b * NKH + kh) * NS * NHD;
    const u16* Vp = Vt + ((size_t)b * NKH + kh) * (size_t)NHD * NS;

    bf16x8 qf[8];
    #pragma unroll
    for (int ds = 0; ds < 8; ++ds)
        qf[ds] = *(const bf16x8*)(Qp + c * NHD + ds * 16 + hi * 8);

    f32x16 o0 = {}, o1 = {}, o2 = {}, o3 = {};
    float m_run = -1e30f, l_run = 0.f;

    auto stageK = [&](int buf, int kt) {
        const int kb = kt << 6;
        #pragma unroll
        for (int ii = 0; ii < 4; ++ii) {           // K: rows r, swizzled col chunks
            int r = w * 16 + ii * 4 + (l >> 4);
            int q = (l & 15) ^ ((ii * 4 + (l >> 4)) & 7);
            const u16* src = Kp + (size_t)(kb + r) * NHD + q * 8;
            __builtin_amdgcn_global_load_lds(
                (const AS1 void*)src,
                (AS3 void*)&kl[buf][(w * 4 + ii) * 512], 16, 0, 0);
        }
    };
    auto stageV = [&](int kt) {
        const int kb = kt << 6;
        #pragma unroll
        for (int ii = 0; ii < 4; ++ii) {           // V: rows d, swizzled kv chunks
            int jj = w * 4 + ii;
            int d = jj * 8 + (l >> 3);
            int q = (l & 7) ^ ((l >> 3) & 7);
            const u16* src = Vp + (size_t)d * NS + kb + q * 8;
            __builtin_amdgcn_global_load_lds(
                (const AS1 void*)src,
                (AS3 void*)&vl[jj * 512], 16, 0, 0);
        }
    };

    const int NT = (g >> 1) + 1;               // exact causal range, 64-kv tiles
    // prologue: K(0), V(0), K(1); wait K(0) only (counted)
    stageK(0, 0);
    stageV(0);
    if (NT > 1) {
        stageK(1, 1);
        asm volatile("s_waitcnt vmcnt(8)" ::: "memory");   // K(0) landed
    } else {
        asm volatile("s_waitcnt vmcnt(4)" ::: "memory");   // K(0) landed
    }
    __builtin_amdgcn_s_barrier();

    for (int kt = 0; kt < NT; ++kt) {
        const int kb = kt << 6;
        const int cur = kt & 1;
        // entry: K(kt) resident; outstanding V(kt)[4] + (kt+1<NT ? K(kt+1)[4] : 0)
        const bool do1 = (kb + 32 <= qend);
        const bool diag0 = (kb == q0);
        const bool diag1 = (kb + 32 == q0);
        const char* Klb = (const char*)kl[cur];
        const char* Vlb = (const char*)vl;

        f32x16 s0 = {}, s1 = {};
        __builtin_amdgcn_s_setprio(1);
        #pragma unroll
        for (int ds = 0; ds < 8; ++ds) {
            bf16x8 kf0 = *(const bf16x8*)(Klb + c * 256 + ((ds * 32 + hi * 16) ^ ((c & 7) << 4)));
            s0 = __builtin_amdgcn_mfma_f32_32x32x16_bf16(kf0, qf[ds], s0, 0, 0, 0);
        }
        if (do1) {
            #pragma unroll
            for (int ds = 0; ds < 8; ++ds) {
                bf16x8 kf1 = *(const bf16x8*)(Klb + (32 + c) * 256 + ((ds * 32 + hi * 16) ^ ((c & 7) << 4)));
                s1 = __builtin_amdgcn_mfma_f32_32x32x16_bf16(kf1, qf[ds], s1, 0, 0, 0);
            }
        }
        __builtin_amdgcn_s_setprio(0);

        float sv0[16], sv1[16];
        #pragma unroll
        for (int r = 0; r < 16; ++r) { sv0[r] = s0[r]; sv1[r] = do1 ? s1[r] : -1e30f; }

        if (diag0 || diag1) {
            #pragma unroll
            for (int r = 0; r < 16; ++r) {
                int rr = (r & 3) + 8 * (r >> 2) + 4 * hi;
                if (diag0) { if (rr > c) sv0[r] = -1e30f; }
                else       { if (rr > c) sv1[r] = -1e30f; }
            }
        }

        float mx = -1e30f;
        #pragma unroll
        for (int r = 0; r < 16; ++r) mx = fmaxf(mx, fmaxf(sv0[r], sv1[r]));
        mx = redmax32(mx);

        if (__any(mx > m_run + 8.0f)) {
            float mnew = fmaxf(m_run, mx);
            float alpha = exp2f(m_run - mnew);
            m_run = mnew;
            l_run *= alpha;
            #pragma unroll
            for (int r = 0; r < 16; ++r) {
                int qr = (r & 3) + 8 * (r >> 2) + 4 * hi;
                float aR = __shfl(alpha, qr + (l & 32));
                o0[r] *= aR; o1[r] *= aR; o2[r] *= aR; o3[r] *= aR;
            }
        }

        float e0[16], e1[16];
        float ls = 0.f;
        #pragma unroll
        for (int r = 0; r < 16; ++r) {
            e0[r] = exp2f(sv0[r] - m_run);
            e1[r] = exp2f(sv1[r] - m_run);
            ls += e0[r] + e1[r];
        }
        l_run += redsum32(ls);

        bf16x8 pa[4];
        #pragma unroll
        for (int ks = 0; ks < 4; ++ks) {
            const float* pe = (ks < 2) ? e0 : e1;
            const int b8 = (ks & 1) * 8;
            unsigned A  = pk2(pe[b8 + 0], pe[b8 + 1]);
            unsigned Bq = pk2(pe[b8 + 4], pe[b8 + 5]);
            unsigned C2 = pk2(pe[b8 + 2], pe[b8 + 3]);
            unsigned D2 = pk2(pe[b8 + 6], pe[b8 + 7]);
            pl32swap(A, Bq);
            pl32swap(C2, D2);
            union { uint4 u; bf16x8 v; } cv;
            cv.u.x = A;
            cv.u.y = C2;
            cv.u.z = Bq;
            cv.u.w = D2;
            pa[ks] = cv.v;
        }

        // V(kt) resident check: counted — K(kt+1) stays in flight
        if (kt + 1 < NT) asm volatile("s_waitcnt vmcnt(4)" ::: "memory");
        else             asm volatile("s_waitcnt vmcnt(0)" ::: "memory");
        __builtin_amdgcn_s_barrier();

        __builtin_amdgcn_s_setprio(1);
        #pragma unroll
        for (int ks = 0; ks < 4; ++ks) {
            if (ks >= 2 && !do1) continue;
            const int ko = (ks * 32 + hi * 16);
            bf16x8 vf;
            vf = *(const bf16x8*)(Vlb + (0 * 32 + c) * 128 + (ko ^ ((c & 7) << 4)));
            o0 = __builtin_amdgcn_mfma_f32_32x32x16_bf16(pa[ks], vf, o0, 0, 0, 0);
            vf = *(const bf16x8*)(Vlb + (1 * 32 + c) * 128 + (ko ^ ((c & 7) << 4)));
            o1 = __builtin_amdgcn_mfma_f32_32x32x16_bf16(pa[ks], vf, o1, 0, 0, 0);
            vf = *(const bf16x8*)(Vlb + (2 * 32 + c) * 128 + (ko ^ ((c & 7) << 4)));
            o2 = __builtin_amdgcn_mfma_f32_32x32x16_bf16(pa[ks], vf, o2, 0, 0, 0);
            vf = *(const bf16x8*)(Vlb + (3 * 32 + c) * 128 + (ko ^ ((c & 7) << 4)));
            o3 = __builtin_amdgcn_mfma_f32_32x32x16_bf16(pa[ks], vf, o3, 0, 0, 0);
        }
        __builtin_amdgcn_s_setprio(0);

        if (kt + 1 < NT) {
            __builtin_amdgcn_s_barrier();          // all waves done reading vl and kl[cur]
            stageV(kt + 1);                        // overwrite vl
            if (kt + 2 < NT) {
                stageK(cur, kt + 2);               // buffer (kt+2)&1 == cur: K(kt) dead
                asm volatile("s_waitcnt vmcnt(8)" ::: "memory");   // K(kt+1) landed
            } else {
                asm volatile("s_waitcnt vmcnt(4)" ::: "memory");   // K(kt+1) landed
            }
            __builtin_amdgcn_s_barrier();          // K(kt+1) resident everywhere
        }
    }

    const float linv = 1.0f / l_run;
    #pragma unroll
    for (int r = 0; r < 16; ++r) {
        int qr = (r & 3) + 8 * (r >> 2) + 4 * hi;
        float lr = __shfl(linv, qr + (l & 32));
        size_t base = ((size_t)(b * NS + q0 + qr)) * (NH * NHD) + h * NHD;
        Out[base + c]      = f2bf(o0[r] * lr);
        Out[base + 32 + c] = f2bf(o1[r] * lr);
        Out[base + 64 + c] = f2bf(o2[r] * lr);
        Out[base + 96 + c] = f2bf(o3[r] * lr);
    }
}

// ---------------- host launcher ----------------
extern "C" void kernel_launch(void* const* d_in, const int* in_sizes, int n_in,
                              void* d_out, int out_size, void* d_ws, size_t ws_size,
                              hipStream_t stream)
{
    (void)in_sizes; (void)n_in; (void)out_size; (void)ws_size;
    const float* hidden = (const float*)d_in[0];
    const float* cosb   = (const float*)d_in[1];
    const float* sinb   = (const float*)d_in[2];
    const float* qkv_w  = (const float*)d_in[3];
    const float* qkv_b  = (const float*)d_in[4];
    const float* o_w    = (const float*)d_in[5];
    float* out = (float*)d_out;

    char* ws = (char*)d_ws;
    size_t off = 0;
    auto alloc = [&](size_t bytes) {
        void* p = ws + off; off += (bytes + 255) & ~(size_t)255; return p;
    };
    u16* hid_bf  = (u16*)alloc((size_t)NB * NS * ND * 2);
    u16* qkvw_bf = (u16*)alloc((size_t)NQKV * ND * 2);
    u16* ow_bf   = (u16*)alloc((size_t)ND * NH * NHD * 2);
    u16* qkv     = (u16*)alloc((size_t)NB * NS * NQKV * 2);
    u16* Qb      = (u16*)alloc((size_t)NB * NH * NS * NHD * 2);
    u16* Kb      = (u16*)alloc((size_t)NB * NKH * NS * NHD * 2);
    u16* Vt      = (u16*)alloc((size_t)NB * NKH * NS * NHD * 2);
    u16* attn    = hid_bf;   // alias: hidden_bf16 dead after GEMM1

    int n1 = NB * NS * ND / 4;
    int n2 = NQKV * ND / 4;
    int n3 = ND * NH * NHD / 4;
    cvt_all<<<(n1 + n2 + n3 + 255) / 256, 256, 0, stream>>>(
        hidden, hid_bf, n1, qkv_w, qkvw_bf, n2, o_w, ow_bf, n3);

    // GEMM1: 128x160 tiles -> 32 x 16 = 512 blocks, exactly 2/CU (no tail)
    int nwg1 = (NB * NS / 128) * (NQKV / 160);     // 512
    gemm_bt<1, 1, 5><<<nwg1, 256, 0, stream>>>(hid_bf, qkvw_bf, qkv_b, qkv,
                                               NB * NS, NQKV, ND, NB * NS / 128, nwg1);

    int nr = NB * NS * NHD;                        // one thread per (bs, d)
    rope_scatter2<<<nr / 256, 256, 0, stream>>>(qkv, cosb, sinb, Qb, Kb, Vt);

    attn_fwd14<<<512, 256, 0, stream>>>(Qb, Kb, Vt, attn);

    int nwg2 = (NB * NS / 128) * (ND / 128);       // 512
    gemm_bt<0, 0, 4><<<nwg2, 256, 0, stream>>>(attn, ow_bf, nullptr, out,
                                               NB * NS, ND, NH * NHD, NB * NS / 128, nwg2);
}